// Round 10
// baseline (50.165 us; speedup 1.0000x reference)
//
#include <hip/hip_runtime.h>

// n = 8192 points, d = 512, fp32 in, scalar fp32 out.
// Pipeline:
//   (1) fp32 -> fp8 e4m3 convert (+ zero-init packed argmax keys)
//   (2) triangular fused MX-fp8 MFMA GEMM (mfma_scale 32x32x64, unit scales
//       = numerically plain fp8, 2x rate, 8x fewer issue slots): 128x128
//       tiles, BK=64 rotation layout, 3-buffer LDS, ONE barrier per K-tile,
//       depth-2 counted-vmcnt staging. Dual row/col argmax with butterfly
//       slot-merge via u64 keys (mono(value)<<32 | ~index).
//   (3) per-row ||x - x[I] + 1e-6||_2 -> log   (full fp32)
//   (4) deterministic mean reduce.

#define NPTS 8192
#define DIM  512
#define BM   128
#define BN   128
#define NTIL 64
#define NBLK (NTIL * (NTIL + 1) / 2)   // 2080 (= 8*260, XCD-divisible)
#define KT_N 8                          // 512 / 64

typedef float f32x16 __attribute__((ext_vector_type(16)));
typedef int   i32x4  __attribute__((ext_vector_type(4)));
typedef int   i32x8  __attribute__((ext_vector_type(8)));

// f32 -> OCP e4m3fn, round-to-nearest-even; N(0,1) data never clamps.
__device__ __forceinline__ unsigned char f32_to_e4m3(float f) {
  unsigned u = __builtin_bit_cast(unsigned, f);
  unsigned s = (u >> 24) & 0x80u;
  unsigned a = u & 0x7FFFFFFFu;
  float af = __builtin_bit_cast(float, a);
  if (af < 0.015625f) {                    // below min normal 2^-6
    int m = (int)rintf(af * 512.0f);       // RNE; 8 naturally -> 2^-6 normal
    return (unsigned char)(s | (unsigned)m);
  }
  unsigned u2 = a + 0x0007FFFFu + ((a >> 20) & 1u);  // RNE to 3-bit mantissa
  int e = (int)(u2 >> 23) - 127 + 7;
  unsigned m = (u2 >> 20) & 7u;
  if (e > 15) return (unsigned char)(s | 0x7Eu);     // clamp to 448
  return (unsigned char)(s | ((unsigned)e << 3) | m);
}

// Order-preserving f32 -> u32 (branchless).
__device__ __forceinline__ unsigned int mono_f32(float f) {
  unsigned u = __builtin_bit_cast(unsigned, f);
  return u ^ (0x80000000u | (unsigned)((int)u >> 31));
}

__global__ void cvt_fp8_kernel(const float* __restrict__ x,
                               unsigned char* __restrict__ xq,
                               unsigned long long* __restrict__ nn64) {
  int i = blockIdx.x * blockDim.x + threadIdx.x;     // 8 elems per thread
  const float4* xp = reinterpret_cast<const float4*>(x) + 2 * (size_t)i;
  float4 v0 = xp[0], v1 = xp[1];
  unsigned long long w =
      (unsigned long long)f32_to_e4m3(v0.x) |
      ((unsigned long long)f32_to_e4m3(v0.y) << 8) |
      ((unsigned long long)f32_to_e4m3(v0.z) << 16) |
      ((unsigned long long)f32_to_e4m3(v0.w) << 24) |
      ((unsigned long long)f32_to_e4m3(v1.x) << 32) |
      ((unsigned long long)f32_to_e4m3(v1.y) << 40) |
      ((unsigned long long)f32_to_e4m3(v1.z) << 48) |
      ((unsigned long long)f32_to_e4m3(v1.w) << 56);
  reinterpret_cast<unsigned long long*>(xq)[i] = w;
  if (i < NPTS) nn64[i] = 0ull;
}

__device__ __forceinline__ void gload_lds16(const unsigned char* g,
                                            unsigned char* l) {
  __builtin_amdgcn_global_load_lds(
      (__attribute__((address_space(1))) const void*)g,
      (__attribute__((address_space(3))) void*)l, 16, 0, 0);
}

__device__ __forceinline__ unsigned long long kmax(unsigned long long a,
                                                   unsigned long long b) {
  return a > b ? a : b;
}

// Triangular fused MX-fp8 GEMM + dual argmax.
// grid = NBLK, block = 256 (4 waves, 2x2 grid of 64x64 sub-tiles; each wave
// = 2x2 of 32x32 MFMA sub-tiles). LDS: 3 x 16 KB -> 3 blocks/CU.
__global__ __launch_bounds__(256, 3) void tri_gemm_kernel(
    const unsigned char* __restrict__ xq,
    unsigned long long* __restrict__ nn64) {
  __shared__ unsigned char lds[3][16384];

  // XCD-bijective swizzle (2080 = 8*260), then b -> (ti >= tj).
  const int orig = (int)blockIdx.x;
  int b = (orig & 7) * (NBLK >> 3) + (orig >> 3);
  int ti = (int)((sqrtf(8.0f * (float)b + 1.0f) - 1.0f) * 0.5f);
  while ((ti + 1) * (ti + 2) / 2 <= b) ++ti;
  while (ti * (ti + 1) / 2 > b) --ti;
  const int tj = b - ti * (ti + 1) / 2;

  const int tid  = (int)threadIdx.x;
  const int wid  = tid >> 6;
  const int lane = tid & 63;
  const int wr   = wid >> 1;      // 0..1
  const int wc   = wid & 1;       // 0..1
  const int l31  = lane & 31;
  const int h    = lane >> 5;     // 0..1 (k-half within MFMA)
  const int arow0 = ti * BM;
  const int bcol0 = tj * BN;

  // Staging: row = 64 B = 4 slots of 16 B. LDS slot s of row r holds global
  // chunk (s - f(r)) & 3 with f(r) = ((r>>1)+(r>>3)) & 3  (period 16 ->
  // 2-way banks for the 32-row x 2-slot b128 read pattern below).
#define STAGE(bufi, kt) do {                                                 \
    _Pragma("unroll")                                                        \
    for (int i_ = 0; i_ < 2; ++i_) {                                         \
      const int chunk_ = (i_ << 8) + tid;          /* 0..511 */              \
      const int row_   = chunk_ >> 2;              /* 0..127 */              \
      const int f_     = ((row_ >> 1) + (row_ >> 3)) & 3;                    \
      const int c_     = ((chunk_ & 3) - f_) & 3;                            \
      gload_lds16(xq + (size_t)(arow0 + row_) * DIM + (kt) * 64 + (c_ << 4), \
                  &lds[bufi][chunk_ << 4]);                                   \
      gload_lds16(xq + (size_t)(bcol0 + row_) * DIM + (kt) * 64 + (c_ << 4), \
                  &lds[bufi][8192 + (chunk_ << 4)]);                          \
    }                                                                        \
  } while (0)

  // Fragment reads (32x32x64): lane l wants row (l&31) of its sub-tile and
  // global k-chunks g0 = 2h, g0+1 (32 contiguous bytes). Stored slots:
  // (g + f) & 3, f = ((l31>>1)+(l31>>3)) & 3 (sub-tile bases are x32).
  const int fr  = ((l31 >> 1) + (l31 >> 3)) & 3;
  const int s0  = (2 * h + fr) & 3;
  const int s1  = (2 * h + 1 + fr) & 3;
  const int abase = (wr * 64 + l31) * 64;
  const int bbase = 8192 + (wc * 64 + l31) * 64;
  const int aoff0 = abase + (s0 << 4), aoff1 = abase + (s1 << 4);
  const int boff0 = bbase + (s0 << 4), boff1 = bbase + (s1 << 4);

  f32x16 acc[2][2];
#pragma unroll
  for (int mi = 0; mi < 2; ++mi)
#pragma unroll
    for (int ni = 0; ni < 2; ++ni)
#pragma unroll
      for (int r = 0; r < 16; ++r) acc[mi][ni][r] = 0.f;

  // Prologue: 2 K-tiles in flight (depth-2).
  STAGE(0, 0);
  STAGE(1, 1);

  // ONE barrier per K-tile (proven R9 schedule): after bar(u), all reads of
  // tile u-1 are retired, so staging tile u+2 into buf[(u+2)%3] is safe.
  for (int u = 0; u < KT_N; ++u) {
    const int cur = u - (u / 3) * 3;            // u % 3
    if (u == KT_N - 1) {
      asm volatile("s_waitcnt vmcnt(0)" ::: "memory");
    } else {
      asm volatile("s_waitcnt vmcnt(4)" ::: "memory");  // tile u landed
    }
    asm volatile("s_barrier" ::: "memory");             // buf[cur] published
    if (u + 2 < KT_N) {
      const int nb = (u + 2) - ((u + 2) / 3) * 3;
      STAGE(nb, u + 2);                                 // depth-2 prefetch
    }

    i32x8 a8[2], b8[2];
#pragma unroll
    for (int mi = 0; mi < 2; ++mi) {
      i32x4 lo = *reinterpret_cast<const i32x4*>(&lds[cur][aoff0 + mi * 2048]);
      i32x4 hi = *reinterpret_cast<const i32x4*>(&lds[cur][aoff1 + mi * 2048]);
      a8[mi] = (i32x8){lo[0], lo[1], lo[2], lo[3], hi[0], hi[1], hi[2], hi[3]};
    }
#pragma unroll
    for (int ni = 0; ni < 2; ++ni) {
      i32x4 lo = *reinterpret_cast<const i32x4*>(&lds[cur][boff0 + ni * 2048]);
      i32x4 hi = *reinterpret_cast<const i32x4*>(&lds[cur][boff1 + ni * 2048]);
      b8[ni] = (i32x8){lo[0], lo[1], lo[2], lo[3], hi[0], hi[1], hi[2], hi[3]};
    }
    __builtin_amdgcn_s_setprio(1);
#pragma unroll
    for (int mi = 0; mi < 2; ++mi)
#pragma unroll
      for (int ni = 0; ni < 2; ++ni)
        acc[mi][ni] = __builtin_amdgcn_mfma_scale_f32_32x32x64_f8f6f4(
            a8[mi], b8[ni], acc[mi][ni], 0, 0,   // cbsz=fp8, blgp=fp8
            0, 0x7F7F7F7F, 0, 0x7F7F7F7F);       // unit E8M0 scales
    __builtin_amdgcn_s_setprio(0);
  }
#undef STAGE

  // ---- Epilogue: dual argmax. 32x32 C/D layout: col = lane&31,
  // row_local = (reg&3) + 8*(reg>>2) + 4*(lane>>5). Key = mono(v)<<32 | ~idx.
  const bool diagw = (ti == tj) && (wr == wc);

  // Row side: 32 slots (mi*16 + r), pre-merged over ni.
  unsigned long long K[32];
  const unsigned jb = ~(unsigned)(bcol0 + wc * 64 + l31);
#pragma unroll
  for (int mi = 0; mi < 2; ++mi)
#pragma unroll
    for (int r = 0; r < 16; ++r) {
      const int rl = (r & 3) + 8 * (r >> 2) + 4 * h;
      unsigned long long best = 0ull;
#pragma unroll
      for (int ni = 0; ni < 2; ++ni) {
        unsigned long long kk =
            ((unsigned long long)mono_f32(acc[mi][ni][r]) << 32) |
            (unsigned)(jb - ni * 32);
        if (diagw && mi == ni && rl == l31) kk = 0ull;
        best = kmax(best, kk);
      }
      K[mi * 16 + r] = best;
    }
  // Slot-halving butterfly over lane bits 0..4 (within each 32-lane half):
  // 31 shuffle-steps; lane ends with slot s = lane&31 fully reduced.
#pragma unroll
  for (int k = 0; k < 5; ++k) {
    const int m = 1 << k;
    const unsigned kb = (unsigned)(lane >> k) & 1u;
#pragma unroll
    for (int i = 0; i < (16 >> k); ++i) {
      unsigned long long lo = K[2 * i], hi = K[2 * i + 1];
      unsigned long long keep = kb ? hi : lo;
      unsigned long long send = kb ? lo : hi;
      unsigned long long recv =
          (unsigned long long)__shfl_xor((long long)send, m);
      K[i] = kmax(keep, recv);
    }
  }
  {
    // slot s = l31: mi = s>>4, r = s&15; row uses this lane's h.
    const int s = l31;
    const int gi = arow0 + wr * 64 + (s >> 4) * 32 +
                   ((s & 3) + 8 * ((s & 15) >> 2) + 4 * h);
    atomicMax(&nn64[gi], K[0]);      // 64 lanes -> 64 distinct rows
  }

  // Col side: in-lane merge over (mi, r) per ni, then one xor-32 exchange.
  {
    unsigned long long C0 = 0ull, C1 = 0ull;
    const unsigned ib = ~(unsigned)(arow0 + wr * 64);
#pragma unroll
    for (int mi = 0; mi < 2; ++mi)
#pragma unroll
      for (int r = 0; r < 16; ++r) {
        const int rl = (r & 3) + 8 * (r >> 2) + 4 * h;
        const unsigned idxk = (unsigned)(ib - (mi * 32 + rl));
        unsigned long long k0 =
            ((unsigned long long)mono_f32(acc[mi][0][r]) << 32) | idxk;
        if (diagw && mi == 0 && rl == l31) k0 = 0ull;
        C0 = kmax(C0, k0);
        unsigned long long k1 =
            ((unsigned long long)mono_f32(acc[mi][1][r]) << 32) | idxk;
        if (diagw && mi == 1 && rl == l31) k1 = 0ull;
        C1 = kmax(C1, k1);
      }
    unsigned long long keep = h ? C1 : C0;
    unsigned long long send = h ? C0 : C1;
    unsigned long long recv =
        (unsigned long long)__shfl_xor((long long)send, 32);
    unsigned long long R = kmax(keep, recv);
    const int gj = bcol0 + wc * 64 + h * 32 + l31;   // 64 distinct cols
    atomicMax(&nn64[gj], R);
  }
}

// rho_r = ||x_r - x_{nn(r)} + 1e-6||_2 ; logs[r] = log(rho + 1e-8).
__global__ void dist_log_kernel(const float* __restrict__ x,
                                const unsigned long long* __restrict__ nn64,
                                float* __restrict__ logs) {
  const int row  = blockIdx.x * 4 + ((int)threadIdx.x >> 6);
  const int lane = (int)threadIdx.x & 63;
  const int nn   = (int)(~(unsigned int)(nn64[row] & 0xFFFFFFFFull)) & (NPTS - 1);
  const float4* xr = reinterpret_cast<const float4*>(x + (size_t)row * DIM);
  const float4* xn = reinterpret_cast<const float4*>(x + (size_t)nn  * DIM);
  float s = 0.f;
#pragma unroll
  for (int i = 0; i < 2; ++i) {
    float4 a = xr[lane + i * 64];
    float4 b = xn[lane + i * 64];
    float d0 = a.x - b.x + 1e-6f;
    float d1 = a.y - b.y + 1e-6f;
    float d2 = a.z - b.z + 1e-6f;
    float d3 = a.w - b.w + 1e-6f;
    s += d0 * d0 + d1 * d1 + d2 * d2 + d3 * d3;
  }
#pragma unroll
  for (int m = 32; m >= 1; m >>= 1) s += __shfl_xor(s, m);
  if (lane == 0) logs[row] = logf(sqrtf(s) + 1e-8f);
}

// Deterministic mean: 1024 threads x 8 sequential adds + LDS tree.
__global__ void final_reduce_kernel(const float* __restrict__ logs,
                                    float* __restrict__ out) {
  __shared__ float sm[1024];
  const int t = (int)threadIdx.x;
  float s = 0.f;
#pragma unroll
  for (int i = 0; i < 8; ++i) s += logs[t * 8 + i];
  sm[t] = s;
  __syncthreads();
  for (int k = 512; k > 0; k >>= 1) {
    if (t < k) sm[t] += sm[t + k];
    __syncthreads();
  }
  if (t == 0) out[0] = -(sm[0] / (float)NPTS);
}

extern "C" void kernel_launch(void* const* d_in, const int* in_sizes, int n_in,
                              void* d_out, int out_size, void* d_ws, size_t ws_size,
                              hipStream_t stream) {
  const float* x = (const float*)d_in[0];
  float* out = (float*)d_out;
  char* ws = (char*)d_ws;

  // Workspace layout (bytes):
  unsigned char*      xq   = (unsigned char*)(ws);                // 4 MB
  unsigned long long* nn64 = (unsigned long long*)(ws + 4194304); // 64 KB
  float*              logs = (float*)(ws + 4259840);              // 32 KB

  cvt_fp8_kernel<<<(NPTS * DIM / 8) / 256, 256, 0, stream>>>(x, xq, nn64);

  tri_gemm_kernel<<<NBLK, 256, 0, stream>>>(xq, nn64);

  dist_log_kernel<<<NPTS / 4, 256, 0, stream>>>(x, nn64, logs);

  final_reduce_kernel<<<1, 1024, 0, stream>>>(logs, out);
}